// Round 3
// baseline (1040.040 us; speedup 1.0000x reference)
//
#include <hip/hip_runtime.h>
#include <hip/hip_bf16.h>
#include <cstdint>

#define NFEAT 128
#define NCLS  64

// ---------------- helpers ----------------

__device__ __forceinline__ int load_idx(const void* ei, long long i, int is64) {
  return is64 ? (int)((const long long*)ei)[i] : ((const int*)ei)[i];
}

// Detect whether edge_index arrived as int64 (little-endian: odd int32 words
// are the high words of non-negative values < 2^31 -> all zero) or int32.
__global__ void k_detect(const int* __restrict__ ei32, int* __restrict__ flag,
                         long long total32) {
  __shared__ int sh[256];
  int tid = threadIdx.x;
  int v = 0;
  for (int i = tid; i < 4096; i += 256) {
    long long idx = 2LL * i + 1;
    if (idx < total32) v |= ei32[idx];
  }
  sh[tid] = v;
  __syncthreads();
  for (int st = 128; st > 0; st >>= 1) {
    if (tid < st) sh[tid] |= sh[tid + st];
    __syncthreads();
  }
  if (tid == 0) flag[0] = (sh[0] == 0) ? 1 : 0;
}

// deg[i] = 1 (self loop weight), cnt[i] = 0
__global__ void k_init(float* __restrict__ deg, int* __restrict__ cnt, int n) {
  int i = blockIdx.x * blockDim.x + threadIdx.x;
  if (i < n) { deg[i] = 1.0f; cnt[i] = 0; }
}

// deg[col] += w, cnt[col] += 1
__global__ void k_accum(const void* __restrict__ ei, const float* __restrict__ w,
                        const int* __restrict__ flag, float* __restrict__ deg,
                        int* __restrict__ cnt, int nnz) {
  int e = blockIdx.x * blockDim.x + threadIdx.x;
  if (e >= nnz) return;
  int is64 = flag[0];
  int col = load_idx(ei, (long long)nnz + e, is64);
  atomicAdd(&deg[col], w[e]);
  atomicAdd(&cnt[col], 1);
}

// deg -> dis = rsqrt(deg) in place (deg >= 1 always)
__global__ void k_dis(float* __restrict__ deg, int n) {
  int i = blockIdx.x * blockDim.x + threadIdx.x;
  if (i < n) deg[i] = rsqrtf(deg[i]);
}

// scan part A: per-1024-element block exclusive scan + block sums
__global__ void k_scanA(const int* __restrict__ cnt, int* __restrict__ off,
                        int* __restrict__ bsums, int n) {
  __shared__ int sh[256];
  int tid = threadIdx.x;
  int base = blockIdx.x * 1024 + tid * 4;
  int v[4];
#pragma unroll
  for (int j = 0; j < 4; ++j) v[j] = (base + j < n) ? cnt[base + j] : 0;
  int tsum = v[0] + v[1] + v[2] + v[3];
  int val = tsum;
  sh[tid] = val;
  __syncthreads();
  for (int ofs = 1; ofs < 256; ofs <<= 1) {
    int t = (tid >= ofs) ? sh[tid - ofs] : 0;
    __syncthreads();
    val += t;
    sh[tid] = val;
    __syncthreads();
  }
  int run = val - tsum;  // exclusive prefix of this thread's 4 elements
#pragma unroll
  for (int j = 0; j < 4; ++j) {
    if (base + j < n) off[base + j] = run;
    run += v[j];
  }
  if (tid == 255) bsums[blockIdx.x] = val;
}

// scan part B: add prefix of block sums (few blocks -> brute-force per block)
__global__ void k_scanAdd(int* __restrict__ off, const int* __restrict__ bsums,
                          int n) {
  __shared__ int sh[256];
  int tid = threadIdx.x;
  int s = 0;
  for (int j = tid; j < (int)blockIdx.x; j += 256) s += bsums[j];
  sh[tid] = s;
  __syncthreads();
  for (int st = 128; st > 0; st >>= 1) {
    if (tid < st) sh[tid] += sh[tid + st];
    __syncthreads();
  }
  int prefix = sh[0];
  int base = blockIdx.x * 1024 + tid * 4;
#pragma unroll
  for (int j = 0; j < 4; ++j)
    if (base + j < n) off[base + j] += prefix;
}

// scatter-fill CSC: (row, normalized weight) per edge; off[col] used as cursor,
// afterwards off[c] == segment end of c.
__global__ void k_fill(const void* __restrict__ ei, const float* __restrict__ w,
                       const int* __restrict__ flag, const float* __restrict__ dis,
                       int* __restrict__ off, int2* __restrict__ csc, int nnz) {
  int e = blockIdx.x * blockDim.x + threadIdx.x;
  if (e >= nnz) return;
  int is64 = flag[0];
  int row = load_idx(ei, e, is64);
  int col = load_idx(ei, (long long)nnz + e, is64);
  float wn = dis[row] * w[e] * dis[col];
  int pos = atomicAdd(&off[col], 1);
  csc[pos] = make_int2(row, __float_as_int(wn));
}

// y0 = X @ W^T : one wave per node, lane = class. W (32 KB) is L1-hot.
__global__ void k_gemm(const float* __restrict__ x, const float* __restrict__ w,
                       float* __restrict__ y, int n) {
  int wave = (blockIdx.x * blockDim.x + threadIdx.x) >> 6;
  int lane = threadIdx.x & 63;
  if (wave >= n) return;
  const float* xr = x + (size_t)wave * NFEAT;
  const float* wr = w + (size_t)lane * NFEAT;
  float acc = 0.0f;
#pragma unroll
  for (int k = 0; k < NFEAT; k += 4) {
    float4 xv = *(const float4*)(xr + k);  // wave-uniform -> broadcast
    float4 wv = *(const float4*)(wr + k);  // per-lane, L1-resident
    acc += xv.x * wv.x + xv.y * wv.y + xv.z * wv.z + xv.w * wv.w;
  }
  y[(size_t)wave * NCLS + lane] = acc;
}

// one hop: yout[c] = dis[c]^2 * yin[c] + sum_e w~_e * yin[row_e]  (+ bias)
__global__ void k_hop(const float* __restrict__ yin, float* __restrict__ yout,
                      const int* __restrict__ ends, const int2* __restrict__ csc,
                      const float* __restrict__ dis, const float* __restrict__ bias,
                      int n) {
  int node = (blockIdx.x * blockDim.x + threadIdx.x) >> 6;
  int lane = threadIdx.x & 63;
  if (node >= n) return;
  int beg = (node == 0) ? 0 : ends[node - 1];
  int end = ends[node];
  float d = dis[node];
  float acc = d * d * yin[(size_t)node * NCLS + lane];
  for (int e = beg; e < end; ++e) {
    int2 m = csc[e];  // wave-uniform 8B load
    acc += __int_as_float(m.y) * yin[(size_t)m.x * NCLS + lane];
  }
  if (bias) acc += bias[lane];
  yout[(size_t)node * NCLS + lane] = acc;
}

// ---------------- launch ----------------

extern "C" void kernel_launch(void* const* d_in, const int* in_sizes, int n_in,
                              void* d_out, int out_size, void* d_ws, size_t ws_size,
                              hipStream_t stream) {
  (void)n_in; (void)out_size; (void)ws_size;
  const float* x  = (const float*)d_in[0];
  const void*  ei = d_in[1];
  const float* ew = (const float*)d_in[2];
  const float* lw = (const float*)d_in[3];
  const float* lb = (const float*)d_in[4];
  float* out = (float*)d_out;

  int n   = in_sizes[0] / NFEAT;
  int nnz = in_sizes[1] / 2;

  char* p = (char*)d_ws;
  auto carve = [&](size_t bytes) -> char* {
    char* r = p;
    p += (bytes + 255) & ~(size_t)255;
    return r;
  };
  int*   flag  = (int*)carve(4);
  float* deg   = (float*)carve((size_t)n * 4);        // becomes dis after k_dis
  int*   cnt   = (int*)carve((size_t)n * 4);
  int*   off   = (int*)carve((size_t)n * 4);
  int    nsb   = (n + 1023) / 1024;
  int*   bsums = (int*)carve((size_t)nsb * 4);
  int2*  csc   = (int2*)carve((size_t)nnz * 8);
  float* y1    = (float*)carve((size_t)n * NCLS * 4);
  float* y0    = out;  // d_out doubles as y0 scratch; final hop overwrites it

  int gb = (n + 255) / 256;
  int ge = (nnz + 255) / 256;
  int gw = (n + 3) / 4;  // 4 waves (nodes) per 256-thread block

  k_detect<<<1, 256, 0, stream>>>((const int*)ei, flag, 2LL * nnz);
  k_init<<<gb, 256, 0, stream>>>(deg, cnt, n);
  k_accum<<<ge, 256, 0, stream>>>(ei, ew, flag, deg, cnt, nnz);
  k_dis<<<gb, 256, 0, stream>>>(deg, n);
  k_scanA<<<nsb, 256, 0, stream>>>(cnt, off, bsums, n);
  k_scanAdd<<<nsb, 256, 0, stream>>>(off, bsums, n);
  k_fill<<<ge, 256, 0, stream>>>(ei, ew, flag, deg, off, csc, nnz);
  k_gemm<<<gw, 256, 0, stream>>>(x, lw, y0, n);
  k_hop<<<gw, 256, 0, stream>>>(y0, y1, off, csc, deg, nullptr, n);
  k_hop<<<gw, 256, 0, stream>>>(y1, out, off, csc, deg, lb, n);
}

// Round 8
// 494.338 us; speedup vs baseline: 2.1039x; 2.1039x over previous
//
#include <hip/hip_runtime.h>
#include <hip/hip_bf16.h>
#include <cstdint>

#define NFEAT 128
#define NCLS  64
#define TM    64   // nodes per GEMM block tile
#define KT    64   // K-tile (2 tiles of 64 over NFEAT=128)
#define LDP   68   // padded LDS row stride (floats): 68%4==0 (16B align), 68%32==4 (bank spread)

// ---------------- helpers ----------------

__device__ __forceinline__ int load_idx(const void* ei, long long i, int is64) {
  return is64 ? (int)((const long long*)ei)[i] : ((const int*)ei)[i];
}

// Detect whether edge_index arrived as int64 (little-endian: odd int32 words
// are the high words of non-negative values < 2^31 -> all zero) or int32.
__global__ void k_detect(const int* __restrict__ ei32, int* __restrict__ flag,
                         long long total32) {
  __shared__ int sh[256];
  int tid = threadIdx.x;
  int v = 0;
  for (int i = tid; i < 4096; i += 256) {
    long long idx = 2LL * i + 1;
    if (idx < total32) v |= ei32[idx];
  }
  sh[tid] = v;
  __syncthreads();
  for (int st = 128; st > 0; st >>= 1) {
    if (tid < st) sh[tid] |= sh[tid + st];
    __syncthreads();
  }
  if (tid == 0) flag[0] = (sh[0] == 0) ? 1 : 0;
}

// deg[i] = 1 (self loop weight), cnt[i] = 0
__global__ void k_init(float* __restrict__ deg, int* __restrict__ cnt, int n) {
  int i = blockIdx.x * blockDim.x + threadIdx.x;
  if (i < n) { deg[i] = 1.0f; cnt[i] = 0; }
}

// deg[col] += w, cnt[col] += 1
__global__ void k_accum(const void* __restrict__ ei, const float* __restrict__ w,
                        const int* __restrict__ flag, float* __restrict__ deg,
                        int* __restrict__ cnt, int nnz) {
  int e = blockIdx.x * blockDim.x + threadIdx.x;
  if (e >= nnz) return;
  int is64 = flag[0];
  int col = load_idx(ei, (long long)nnz + e, is64);
  atomicAdd(&deg[col], w[e]);
  atomicAdd(&cnt[col], 1);
}

// deg -> dis = rsqrt(deg) in place (deg >= 1 always)
__global__ void k_dis(float* __restrict__ deg, int n) {
  int i = blockIdx.x * blockDim.x + threadIdx.x;
  if (i < n) deg[i] = rsqrtf(deg[i]);
}

// scan part A: per-1024-element block exclusive scan + block sums
__global__ void k_scanA(const int* __restrict__ cnt, int* __restrict__ off,
                        int* __restrict__ bsums, int n) {
  __shared__ int sh[256];
  int tid = threadIdx.x;
  int base = blockIdx.x * 1024 + tid * 4;
  int v[4];
#pragma unroll
  for (int j = 0; j < 4; ++j) v[j] = (base + j < n) ? cnt[base + j] : 0;
  int tsum = v[0] + v[1] + v[2] + v[3];
  int val = tsum;
  sh[tid] = val;
  __syncthreads();
  for (int ofs = 1; ofs < 256; ofs <<= 1) {
    int t = (tid >= ofs) ? sh[tid - ofs] : 0;
    __syncthreads();
    val += t;
    sh[tid] = val;
    __syncthreads();
  }
  int run = val - tsum;  // exclusive prefix of this thread's 4 elements
#pragma unroll
  for (int j = 0; j < 4; ++j) {
    if (base + j < n) off[base + j] = run;
    run += v[j];
  }
  if (tid == 255) bsums[blockIdx.x] = val;
}

// scan part B: add prefix of block sums (few blocks -> brute-force per block)
__global__ void k_scanAdd(int* __restrict__ off, const int* __restrict__ bsums,
                          int n) {
  __shared__ int sh[256];
  int tid = threadIdx.x;
  int s = 0;
  for (int j = tid; j < (int)blockIdx.x; j += 256) s += bsums[j];
  sh[tid] = s;
  __syncthreads();
  for (int st = 128; st > 0; st >>= 1) {
    if (tid < st) sh[tid] += sh[tid + st];
    __syncthreads();
  }
  int prefix = sh[0];
  int base = blockIdx.x * 1024 + tid * 4;
#pragma unroll
  for (int j = 0; j < 4; ++j)
    if (base + j < n) off[base + j] += prefix;
}

// scatter-fill CSC: (row, normalized weight) per edge; off[col] used as cursor,
// afterwards off[c] == segment end of c.
__global__ void k_fill(const void* __restrict__ ei, const float* __restrict__ w,
                       const int* __restrict__ flag, const float* __restrict__ dis,
                       int* __restrict__ off, int2* __restrict__ csc, int nnz) {
  int e = blockIdx.x * blockDim.x + threadIdx.x;
  if (e >= nnz) return;
  int is64 = flag[0];
  int row = load_idx(ei, e, is64);
  int col = load_idx(ei, (long long)nnz + e, is64);
  float wn = dis[row] * w[e] * dis[col];
  int pos = atomicAdd(&off[col], 1);
  csc[pos] = make_int2(row, __float_as_int(wn));
}

// y0 = X @ W^T, LDS-tiled, K split in two 64-wide tiles (LDS < 64 KB).
// xt[kk][node] (transposed X K-tile), wt[kk][cls] (W^T K-tile), stride LDP.
// Thread (tn = t&15, tc = t>>4) computes a 4x4 register tile.
__global__ __launch_bounds__(256) void k_gemm(const float* __restrict__ x,
                                              const float* __restrict__ w,
                                              float* __restrict__ y, int n) {
  __shared__ float xt[KT][LDP];
  __shared__ float wt[KT][LDP];
  int t = threadIdx.x;
  int bm = blockIdx.x * TM;

  int tn = t & 15;   // node group
  int tc = t >> 4;   // class group
  float acc[4][4];
#pragma unroll
  for (int a = 0; a < 4; ++a)
#pragma unroll
    for (int b = 0; b < 4; ++b) acc[a][b] = 0.f;

  for (int kt = 0; kt < NFEAT; kt += KT) {
    __syncthreads();
    // stage W^T K-tile: wt[kk][cls] = w[cls*128 + kt + kk]
    for (int i = t; i < NCLS * KT; i += 256) {
      int kk = i & (KT - 1), cls = i >> 6;  // per-wave: cls uniform, kk = lane
      wt[kk][cls] = w[(size_t)cls * NFEAT + kt + kk];
    }
    // stage X K-tile transposed: thread t covers k0=(t&15)*4, nodes nloc+16*i
    int k0   = (t & 15) * 4;
    int nloc = t >> 4;
#pragma unroll
    for (int i = 0; i < 4; ++i) {
      int node = bm + nloc + 16 * i;
      float4 v = make_float4(0.f, 0.f, 0.f, 0.f);
      if (node < n) v = *(const float4*)(x + (size_t)node * NFEAT + kt + k0);
      xt[k0 + 0][nloc + 16 * i] = v.x;
      xt[k0 + 1][nloc + 16 * i] = v.y;
      xt[k0 + 2][nloc + 16 * i] = v.z;
      xt[k0 + 3][nloc + 16 * i] = v.w;
    }
    __syncthreads();

#pragma unroll 4
    for (int k = 0; k < KT; ++k) {
      float4 xv = *(const float4*)&xt[k][tn * 4];
      float4 wv = *(const float4*)&wt[k][tc * 4];
      acc[0][0] += xv.x * wv.x; acc[0][1] += xv.x * wv.y;
      acc[0][2] += xv.x * wv.z; acc[0][3] += xv.x * wv.w;
      acc[1][0] += xv.y * wv.x; acc[1][1] += xv.y * wv.y;
      acc[1][2] += xv.y * wv.z; acc[1][3] += xv.y * wv.w;
      acc[2][0] += xv.z * wv.x; acc[2][1] += xv.z * wv.y;
      acc[2][2] += xv.z * wv.z; acc[2][3] += xv.z * wv.w;
      acc[3][0] += xv.w * wv.x; acc[3][1] += xv.w * wv.y;
      acc[3][2] += xv.w * wv.z; acc[3][3] += xv.w * wv.w;
    }
  }

#pragma unroll
  for (int a = 0; a < 4; ++a) {
    int node = bm + tn * 4 + a;
    if (node < n)
      *(float4*)(y + (size_t)node * NCLS + tc * 4) =
          make_float4(acc[a][0], acc[a][1], acc[a][2], acc[a][3]);
  }
}

// one hop: yout[c] = dis[c]^2 * yin[c] + sum_e w~_e * yin[row_e]  (+ bias)
// Edge meta loaded cooperatively (lane e reads csc[beg+e]), then broadcast
// per-edge via v_readlane; gathers unrolled x4 for memory-level parallelism.
__global__ void k_hop(const float* __restrict__ yin, float* __restrict__ yout,
                      const int* __restrict__ ends, const int2* __restrict__ csc,
                      const float* __restrict__ dis, const float* __restrict__ bias,
                      int n) {
  int node = (blockIdx.x * blockDim.x + threadIdx.x) >> 6;
  int lane = threadIdx.x & 63;
  if (node >= n) return;
  int beg = (node == 0) ? 0 : ends[node - 1];
  int end = ends[node];
  float d = dis[node];
  float acc = d * d * yin[(size_t)node * NCLS + lane];

  for (int base = beg; base < end; base += 64) {
    int cnt = min(64, end - base);
    int2 m = make_int2(0, 0);
    if (lane < cnt) m = csc[base + lane];
    int e = 0;
    for (; e + 4 <= cnt; e += 4) {
      int r0 = __builtin_amdgcn_readlane(m.x, e + 0);
      int r1 = __builtin_amdgcn_readlane(m.x, e + 1);
      int r2 = __builtin_amdgcn_readlane(m.x, e + 2);
      int r3 = __builtin_amdgcn_readlane(m.x, e + 3);
      float w0 = __int_as_float(__builtin_amdgcn_readlane(m.y, e + 0));
      float w1 = __int_as_float(__builtin_amdgcn_readlane(m.y, e + 1));
      float w2 = __int_as_float(__builtin_amdgcn_readlane(m.y, e + 2));
      float w3 = __int_as_float(__builtin_amdgcn_readlane(m.y, e + 3));
      float v0 = yin[(size_t)r0 * NCLS + lane];
      float v1 = yin[(size_t)r1 * NCLS + lane];
      float v2 = yin[(size_t)r2 * NCLS + lane];
      float v3 = yin[(size_t)r3 * NCLS + lane];
      acc += w0 * v0;
      acc += w1 * v1;
      acc += w2 * v2;
      acc += w3 * v3;
    }
    for (; e < cnt; ++e) {
      int r = __builtin_amdgcn_readlane(m.x, e);
      float wv = __int_as_float(__builtin_amdgcn_readlane(m.y, e));
      acc += wv * yin[(size_t)r * NCLS + lane];
    }
  }
  if (bias) acc += bias[lane];
  yout[(size_t)node * NCLS + lane] = acc;
}

// ---------------- launch ----------------

extern "C" void kernel_launch(void* const* d_in, const int* in_sizes, int n_in,
                              void* d_out, int out_size, void* d_ws, size_t ws_size,
                              hipStream_t stream) {
  (void)n_in; (void)out_size; (void)ws_size;
  const float* x  = (const float*)d_in[0];
  const void*  ei = d_in[1];
  const float* ew = (const float*)d_in[2];
  const float* lw = (const float*)d_in[3];
  const float* lb = (const float*)d_in[4];
  float* out = (float*)d_out;

  int n   = in_sizes[0] / NFEAT;
  int nnz = in_sizes[1] / 2;

  char* p = (char*)d_ws;
  auto carve = [&](size_t bytes) -> char* {
    char* r = p;
    p += (bytes + 255) & ~(size_t)255;
    return r;
  };
  int*   flag  = (int*)carve(4);
  float* deg   = (float*)carve((size_t)n * 4);        // becomes dis after k_dis
  int*   cnt   = (int*)carve((size_t)n * 4);
  int*   off   = (int*)carve((size_t)n * 4);
  int    nsb   = (n + 1023) / 1024;
  int*   bsums = (int*)carve((size_t)nsb * 4);
  int2*  csc   = (int2*)carve((size_t)nnz * 8);
  float* y1    = (float*)carve((size_t)n * NCLS * 4);
  float* y0    = out;  // d_out doubles as y0 scratch; final hop overwrites it

  int gb = (n + 255) / 256;
  int ge = (nnz + 255) / 256;
  int gw = (n + 3) / 4;           // hop: 4 node-waves per 256-thread block
  int gg = (n + TM - 1) / TM;     // gemm tiles

  k_detect<<<1, 256, 0, stream>>>((const int*)ei, flag, 2LL * nnz);
  k_init<<<gb, 256, 0, stream>>>(deg, cnt, n);
  k_accum<<<ge, 256, 0, stream>>>(ei, ew, flag, deg, cnt, nnz);
  k_dis<<<gb, 256, 0, stream>>>(deg, n);
  k_scanA<<<nsb, 256, 0, stream>>>(cnt, off, bsums, n);
  k_scanAdd<<<nsb, 256, 0, stream>>>(off, bsums, n);
  k_fill<<<ge, 256, 0, stream>>>(ei, ew, flag, deg, off, csc, nnz);
  k_gemm<<<gg, 256, 0, stream>>>(x, lw, y0, n);
  k_hop<<<gw, 256, 0, stream>>>(y0, y1, off, csc, deg, nullptr, n);
  k_hop<<<gw, 256, 0, stream>>>(y1, out, off, csc, deg, lb, n);
}

// Round 9
// 344.592 us; speedup vs baseline: 3.0182x; 1.4346x over previous
//
#include <hip/hip_runtime.h>
#include <hip/hip_bf16.h>
#include <hip/hip_fp16.h>
#include <cstdint>

#define NFEAT 128
#define NCLS  64
#define TM    64   // nodes per GEMM block tile
#define KT    64   // K-tile (2 tiles of 64 over NFEAT=128)
#define LDP   68   // padded LDS row stride (floats)
#define FIXS  16777216.0f  // 2^24 fixed-point scale for weight sums

typedef unsigned long long u64;
typedef unsigned short u16;

// ---------------- helpers ----------------

__device__ __forceinline__ int load_idx(const void* ei, long long i, int is64) {
  return is64 ? (int)((const long long*)ei)[i] : ((const int*)ei)[i];
}

// Detect int64 vs int32 edge_index (odd 32-bit words all zero -> int64).
__global__ void k_detect(const int* __restrict__ ei32, int* __restrict__ flag,
                         long long total32) {
  __shared__ int sh[256];
  int tid = threadIdx.x;
  int v = 0;
  for (int i = tid; i < 4096; i += 256) {
    long long idx = 2LL * i + 1;
    if (idx < total32) v |= ei32[idx];
  }
  sh[tid] = v;
  __syncthreads();
  for (int st = 128; st > 0; st >>= 1) {
    if (tid < st) sh[tid] |= sh[tid + st];
    __syncthreads();
  }
  if (tid == 0) flag[0] = (sh[0] == 0) ? 1 : 0;
}

// packed[i] = 0  (count<<40 | fixedpoint weight sum)
__global__ void k_init(u64* __restrict__ packed, int n) {
  int i = blockIdx.x * blockDim.x + threadIdx.x;
  if (i < n) packed[i] = 0ULL;
}

// ONE u64 atomic per edge: count in [40:63], sum(w * 2^24) in [0:39].
// Returned old count == this edge's rank within its column segment.
__global__ void k_accum(const void* __restrict__ ei, const float* __restrict__ w,
                        const int* __restrict__ flag, u64* __restrict__ packed,
                        u16* __restrict__ rank, int nnz) {
  int e = blockIdx.x * blockDim.x + threadIdx.x;
  if (e >= nnz) return;
  int is64 = flag[0];
  int col = load_idx(ei, (long long)nnz + e, is64);
  u64 add = (1ULL << 40) | (u64)(unsigned int)__float2uint_rn(w[e] * FIXS);
  u64 old = atomicAdd(&packed[col], add);
  rank[e] = (u16)(old >> 40);
}

// scan part A: per-1024 block exclusive scan of counts (from packed) + sums
__global__ void k_scanA(const u64* __restrict__ packed, int* __restrict__ off,
                        int* __restrict__ bsums, int n) {
  __shared__ int sh[256];
  int tid = threadIdx.x;
  int base = blockIdx.x * 1024 + tid * 4;
  int v[4];
#pragma unroll
  for (int j = 0; j < 4; ++j)
    v[j] = (base + j < n) ? (int)(packed[base + j] >> 40) : 0;
  int tsum = v[0] + v[1] + v[2] + v[3];
  int val = tsum;
  sh[tid] = val;
  __syncthreads();
  for (int ofs = 1; ofs < 256; ofs <<= 1) {
    int t = (tid >= ofs) ? sh[tid - ofs] : 0;
    __syncthreads();
    val += t;
    sh[tid] = val;
    __syncthreads();
  }
  int run = val - tsum;
#pragma unroll
  for (int j = 0; j < 4; ++j) {
    if (base + j < n) off[base + j] = run;
    run += v[j];
  }
  if (tid == 255) bsums[blockIdx.x] = val;
}

// scan part B + epilogue: finalize exclusive offsets; emit offx[n+1],
// colinfo {dis_bits, base}, dis[] (dis = rsqrt(1 + fixsum/2^24)).
__global__ void k_scanB(int* __restrict__ off, const int* __restrict__ bsums,
                        const u64* __restrict__ packed, int* __restrict__ offx,
                        int2* __restrict__ colinfo, float* __restrict__ dis,
                        int n, int nnz) {
  __shared__ int sh[256];
  int tid = threadIdx.x;
  int s = 0;
  for (int j = tid; j < (int)blockIdx.x; j += 256) s += bsums[j];
  sh[tid] = s;
  __syncthreads();
  for (int st = 128; st > 0; st >>= 1) {
    if (tid < st) sh[tid] += sh[tid + st];
    __syncthreads();
  }
  int prefix = sh[0];
  int base = blockIdx.x * 1024 + tid * 4;
#pragma unroll
  for (int j = 0; j < 4; ++j) {
    int i = base + j;
    if (i < n) {
      int b = off[i] + prefix;
      u64 p = packed[i];
      float d = rsqrtf(1.0f + (float)(p & ((1ULL << 40) - 1)) * (1.0f / FIXS));
      offx[i] = b;
      colinfo[i] = make_int2(__float_as_int(d), b);
      dis[i] = d;
    }
  }
  if (blockIdx.x == 0 && tid == 0) offx[n] = nnz;
}

// atomic-free CSC fill: pos = colinfo[col].base + rank[e]
__global__ void k_fill(const void* __restrict__ ei, const float* __restrict__ w,
                       const int* __restrict__ flag, const float* __restrict__ dis,
                       const int2* __restrict__ colinfo, const u16* __restrict__ rank,
                       int2* __restrict__ csc, int nnz) {
  int e = blockIdx.x * blockDim.x + threadIdx.x;
  if (e >= nnz) return;
  int is64 = flag[0];
  int row = load_idx(ei, e, is64);
  int col = load_idx(ei, (long long)nnz + e, is64);
  int2 ci = colinfo[col];
  float wn = dis[row] * w[e] * __int_as_float(ci.x);
  csc[ci.y + (int)rank[e]] = make_int2(row, __float_as_int(wn));
}

// y0 = X @ W^T, LDS-tiled (two 64-wide K-tiles), fp16 output.
__global__ __launch_bounds__(256) void k_gemm(const float* __restrict__ x,
                                              const float* __restrict__ w,
                                              __half* __restrict__ y, int n) {
  __shared__ float xt[KT][LDP];
  __shared__ float wt[KT][LDP];
  int t = threadIdx.x;
  int bm = blockIdx.x * TM;

  int tn = t & 15;
  int tc = t >> 4;
  float acc[4][4];
#pragma unroll
  for (int a = 0; a < 4; ++a)
#pragma unroll
    for (int b = 0; b < 4; ++b) acc[a][b] = 0.f;

  for (int kt = 0; kt < NFEAT; kt += KT) {
    __syncthreads();
    for (int i = t; i < NCLS * KT; i += 256) {
      int kk = i & (KT - 1), cls = i >> 6;
      wt[kk][cls] = w[(size_t)cls * NFEAT + kt + kk];
    }
    int k0   = (t & 15) * 4;
    int nloc = t >> 4;
#pragma unroll
    for (int i = 0; i < 4; ++i) {
      int node = bm + nloc + 16 * i;
      float4 v = make_float4(0.f, 0.f, 0.f, 0.f);
      if (node < n) v = *(const float4*)(x + (size_t)node * NFEAT + kt + k0);
      xt[k0 + 0][nloc + 16 * i] = v.x;
      xt[k0 + 1][nloc + 16 * i] = v.y;
      xt[k0 + 2][nloc + 16 * i] = v.z;
      xt[k0 + 3][nloc + 16 * i] = v.w;
    }
    __syncthreads();

#pragma unroll 4
    for (int k = 0; k < KT; ++k) {
      float4 xv = *(const float4*)&xt[k][tn * 4];
      float4 wv = *(const float4*)&wt[k][tc * 4];
      acc[0][0] += xv.x * wv.x; acc[0][1] += xv.x * wv.y;
      acc[0][2] += xv.x * wv.z; acc[0][3] += xv.x * wv.w;
      acc[1][0] += xv.y * wv.x; acc[1][1] += xv.y * wv.y;
      acc[1][2] += xv.y * wv.z; acc[1][3] += xv.y * wv.w;
      acc[2][0] += xv.z * wv.x; acc[2][1] += xv.z * wv.y;
      acc[2][2] += xv.z * wv.z; acc[2][3] += xv.z * wv.w;
      acc[3][0] += xv.w * wv.x; acc[3][1] += xv.w * wv.y;
      acc[3][2] += xv.w * wv.z; acc[3][3] += xv.w * wv.w;
    }
  }

#pragma unroll
  for (int a = 0; a < 4; ++a) {
    int node = bm + tn * 4 + a;
    if (node < n) {
      __half2* dst = (__half2*)(y + (size_t)node * NCLS + tc * 4);
      dst[0] = __floats2half2_rn(acc[a][0], acc[a][1]);
      dst[1] = __floats2half2_rn(acc[a][2], acc[a][3]);
    }
  }
}

// one hop over fp16 y: acc_f32 = dis^2*yin[c] + sum w~ * yin[row]; FINAL adds
// bias and writes f32 to out, else writes fp16.
template <int FINAL>
__global__ void k_hop(const __half* __restrict__ yin, __half* __restrict__ youth,
                      float* __restrict__ youtf, const int* __restrict__ offx,
                      const int2* __restrict__ csc, const float* __restrict__ dis,
                      const float* __restrict__ bias, int n) {
  int node = (blockIdx.x * blockDim.x + threadIdx.x) >> 6;
  int lane = threadIdx.x & 63;
  if (node >= n) return;
  int beg = offx[node];
  int end = offx[node + 1];
  float d = dis[node];
  float acc = d * d * __half2float(yin[(size_t)node * NCLS + lane]);

  for (int base = beg; base < end; base += 64) {
    int cnt = min(64, end - base);
    int2 m = make_int2(0, 0);
    if (lane < cnt) m = csc[base + lane];
    int e = 0;
    for (; e + 4 <= cnt; e += 4) {
      int r0 = __builtin_amdgcn_readlane(m.x, e + 0);
      int r1 = __builtin_amdgcn_readlane(m.x, e + 1);
      int r2 = __builtin_amdgcn_readlane(m.x, e + 2);
      int r3 = __builtin_amdgcn_readlane(m.x, e + 3);
      float w0 = __int_as_float(__builtin_amdgcn_readlane(m.y, e + 0));
      float w1 = __int_as_float(__builtin_amdgcn_readlane(m.y, e + 1));
      float w2 = __int_as_float(__builtin_amdgcn_readlane(m.y, e + 2));
      float w3 = __int_as_float(__builtin_amdgcn_readlane(m.y, e + 3));
      float v0 = __half2float(yin[(size_t)r0 * NCLS + lane]);
      float v1 = __half2float(yin[(size_t)r1 * NCLS + lane]);
      float v2 = __half2float(yin[(size_t)r2 * NCLS + lane]);
      float v3 = __half2float(yin[(size_t)r3 * NCLS + lane]);
      acc += w0 * v0;
      acc += w1 * v1;
      acc += w2 * v2;
      acc += w3 * v3;
    }
    for (; e < cnt; ++e) {
      int r = __builtin_amdgcn_readlane(m.x, e);
      float wv = __int_as_float(__builtin_amdgcn_readlane(m.y, e));
      acc += wv * __half2float(yin[(size_t)r * NCLS + lane]);
    }
  }
  if (FINAL) {
    youtf[(size_t)node * NCLS + lane] = acc + bias[lane];
  } else {
    youth[(size_t)node * NCLS + lane] = __float2half(acc);
  }
}

// ---------------- launch ----------------

extern "C" void kernel_launch(void* const* d_in, const int* in_sizes, int n_in,
                              void* d_out, int out_size, void* d_ws, size_t ws_size,
                              hipStream_t stream) {
  (void)n_in; (void)out_size; (void)ws_size;
  const float* x  = (const float*)d_in[0];
  const void*  ei = d_in[1];
  const float* ew = (const float*)d_in[2];
  const float* lw = (const float*)d_in[3];
  const float* lb = (const float*)d_in[4];
  float* out = (float*)d_out;

  int n   = in_sizes[0] / NFEAT;
  int nnz = in_sizes[1] / 2;

  char* p = (char*)d_ws;
  auto carve = [&](size_t bytes) -> char* {
    char* r = p;
    p += (bytes + 255) & ~(size_t)255;
    return r;
  };
  int*    flag    = (int*)carve(4);
  u64*    packed  = (u64*)carve((size_t)n * 8);
  u16*    rank    = (u16*)carve((size_t)nnz * 2);
  int*    off     = (int*)carve((size_t)n * 4);
  int     nsb     = (n + 1023) / 1024;
  int*    bsums   = (int*)carve((size_t)nsb * 4);
  int*    offx    = (int*)carve((size_t)(n + 1) * 4);
  int2*   colinfo = (int2*)carve((size_t)n * 8);
  float*  dis     = (float*)carve((size_t)n * 4);
  int2*   csc     = (int2*)carve((size_t)nnz * 8);
  __half* y0      = (__half*)carve((size_t)n * NCLS * 2);
  __half* y1      = (__half*)carve((size_t)n * NCLS * 2);

  int gb = (n + 255) / 256;
  int ge = (nnz + 255) / 256;
  int gw = (n + 3) / 4;           // hop: 4 node-waves per 256-thread block
  int gg = (n + TM - 1) / TM;     // gemm tiles

  k_detect<<<1, 256, 0, stream>>>((const int*)ei, flag, 2LL * nnz);
  k_init<<<gb, 256, 0, stream>>>(packed, n);
  k_accum<<<ge, 256, 0, stream>>>(ei, ew, flag, packed, rank, nnz);
  k_scanA<<<nsb, 256, 0, stream>>>(packed, off, bsums, n);
  k_scanB<<<nsb, 256, 0, stream>>>(off, bsums, packed, offx, colinfo, dis, n, nnz);
  k_fill<<<ge, 256, 0, stream>>>(ei, ew, flag, dis, colinfo, rank, csc, nnz);
  k_gemm<<<gg, 256, 0, stream>>>(x, lw, y0, n);
  k_hop<0><<<gw, 256, 0, stream>>>(y0, y1, nullptr, offx, csc, dis, nullptr, n);
  k_hop<1><<<gw, 256, 0, stream>>>(y1, nullptr, out, offx, csc, dis, lb, n);
}